// Round 10
// baseline (224.514 us; speedup 1.0000x reference)
//
#include <hip/hip_runtime.h>
#include <math.h>

// Problem constants (fixed): B=4, C=256, H=64, W=128, D=4, 81 shifts, C/R=16
// out: [B, 81, H, W] fp32 (2,654,208 elements)
// ws (floats): [0) pooled 82,944  [82944) At 82,944  [165888) cpart 2,654,208

#define HH 64
#define WW 128
#define CC 256
#define BB 4

// ---------------------------------------------------------------------------
// Kernel A: pooled[b, s, c] = sum_{h,w} f1[b,c,h,w] * f2pad[b,c,h+i,w+j]
// UNCHANGED from rounds 8/9 (C should now drop below A, so A finally gets
// top-5 counters next round).
// ---------------------------------------------------------------------------
__global__ __launch_bounds__(576) void corr_pool_kernel(
    const float* __restrict__ f1, const float* __restrict__ f2,
    float* __restrict__ pooled) {
  const int t  = threadIdx.x;
  const int bc = blockIdx.x;                    // b*256 + c
  const float* f1p = f1 + (size_t)bc * (HH * WW);
  const float* f2p = f2 + (size_t)bc * (HH * WW);

  __shared__ float4 f2s4[72 * 35];              // 40,320 B; reused for reduce

  const float4 z4 = make_float4(0.f, 0.f, 0.f, 0.f);
  for (int u = t; u < 72 * 35; u += 576) {
    const int rl = u / 35, k = u - rl * 35;     // padded row, padded chunk
    const int gr = rl - 4;                      // f2 row
    float4 v = z4;
    if ((unsigned)gr < 64u && k >= 1 && k <= 32)
      v = *(const float4*)(f2p + (gr << 7) + ((k - 1) << 2));
    f2s4[u] = v;
  }
  __syncthreads();

  const int h  = t / 9;                         // 0..63
  const int di = t - h * 9;                     // 0..8
  const float4* f2row = &f2s4[(h + di) * 35];   // padded row h+di
  const float* f1row  = f1p + (h << 7);

  float s9[9];
#pragma unroll
  for (int j = 0; j < 9; ++j) s9[j] = 0.f;

  alignas(16) float f1c[16], f2wc[24];
#pragma unroll
  for (int m = 0; m < 4; ++m)
    *(float4*)&f1c[4 * m] = *(const float4*)(f1row + (m << 2));
#pragma unroll
  for (int m = 0; m < 6; ++m) *(float4*)&f2wc[4 * m] = f2row[m];

  for (int seg = 0; seg < 8; ++seg) {
    const int nxt = (seg < 7) ? seg + 1 : 7;    // clamped (dup load on last)
    alignas(16) float f1n[16], f2wn[24];
#pragma unroll
    for (int m = 0; m < 4; ++m)
      *(float4*)&f1n[4 * m] =
          *(const float4*)(f1row + (nxt << 4) + (m << 2));
#pragma unroll
    for (int m = 0; m < 6; ++m) *(float4*)&f2wn[4 * m] = f2row[(nxt << 2) + m];

#pragma unroll
    for (int k = 0; k < 16; ++k) {
      const float a = f1c[k];
#pragma unroll
      for (int j = 0; j < 9; ++j) s9[j] += a * f2wc[k + j];
    }
#pragma unroll
    for (int m = 0; m < 16; ++m) f1c[m] = f1n[m];
#pragma unroll
    for (int m = 0; m < 24; ++m) f2wc[m] = f2wn[m];
  }

  __syncthreads();                              // stage-1 LDS reads done
  float* red  = (float*)f2s4;                   // [64][81]
  float* red2 = red + 64 * 81;                  // [7][81]
#pragma unroll
  for (int j = 0; j < 9; ++j) red[h * 81 + di * 9 + j] = s9[j];
  __syncthreads();

  if (t < 567) {                                // 7 groups x 81 cols
    const int col = t % 81, g = t / 81;
    const int r0 = g * 9, r1 = (g == 6) ? 64 : r0 + 9;
    float acc = 0.f;
#pragma unroll 3
    for (int rr = r0; rr < r1; ++rr) acc += red[rr * 81 + col];
    red2[g * 81 + col] = acc;
  }
  __syncthreads();

  if (t < 81) {
    float acc = 0.f;
#pragma unroll
    for (int g = 0; g < 7; ++g) acc += red2[g * 81 + t];
    const int b = bc >> 8, c = bc & 255;
    pooled[(size_t)(b * 81 + t) * 256 + c] = acc;   // raw sum (/8192 in B)
  }
}

// ---------------------------------------------------------------------------
// Kernel B: At[b, c, s] = sigmoid(MLP(pooled/8192)). Transposed output.
// ---------------------------------------------------------------------------
__global__ __launch_bounds__(256) void mlp_kernel(
    const float* __restrict__ pooled, const float* __restrict__ w1,
    const float* __restrict__ b1, const float* __restrict__ w2,
    const float* __restrict__ b2, float* __restrict__ At) {
  const int bs = blockIdx.x;                    // b*81 + s
  const int t  = threadIdx.x;
  const int b  = bs / 81;
  const int s  = bs - b * 81;
  __shared__ float p[256];
  __shared__ float hid[16];

  p[t] = pooled[(size_t)bs * 256 + t] * (1.0f / 8192.0f);
  __syncthreads();

  const int g = t >> 4, ln = t & 15;
  float acc = 0.f;
#pragma unroll
  for (int m = 0; m < 16; ++m) {
    const int c = (m << 4) + ln;
    acc += w1[(g << 8) + c] * p[c];
  }
  acc += __shfl_xor(acc, 1);
  acc += __shfl_xor(acc, 2);
  acc += __shfl_xor(acc, 4);
  acc += __shfl_xor(acc, 8);
  if (ln == 0) hid[g] = acc + b1[g];
  __syncthreads();

  float acc2 = b2[t];
#pragma unroll
  for (int k = 0; k < 16; ++k) acc2 += w2[(t << 4) + k] * hid[k];
  const float sv = 1.0f / (1.0f + __expf(-acc2));
  At[((size_t)(b * 256 + t)) * 81 + s] = sv;    // transposed: [b][c][81]
}

// ---------------------------------------------------------------------------
// Kernel C (round-10 rewrite): LDS-staged, all-9-i blocks.
// grid = 256 blocks (4b x 32 two-row tiles x 2 channel-halves) = exactly
// 1 block/CU. 576 threads = 9 waves; wave wv computes shift-row i = wv.
// Per 4-channel group, stage into LDS (double-buffered, 51.7 KB):
//   f2 rows h0-4..h0+5 zero-padded to 136 floats (halo IN LDS -> no edge
//   selects in the inner loop) + f1 rows h0,h0+1. 404 float4 / channel.
// All 9 i-waves share one staging (9x L2-traffic cut vs round 9); the 3
// f2-window reads come from LDS (~12 cyc) instead of L2 (~900 under load).
// Per channel per CU: LDS pipe ~508 cyc (bound), VALU 297 cyc/SIMD.
// No min-waves launch bound (r6 spill lesson); watch WRITE_SIZE >> 21 MB.
// ---------------------------------------------------------------------------
#define SCH 4
__global__ __launch_bounds__(576) void out_kernel(
    const float* __restrict__ f1, const float* __restrict__ f2,
    const float* __restrict__ At, float* __restrict__ out,
    float* __restrict__ part) {
  const int bid  = blockIdx.x;
  const int half = bid & 1;
  const int rt   = (bid >> 1) & 31;
  const int b    = bid >> 6;
  const int h0   = rt << 1;

  const int t    = threadIdx.x;
  const int i    = t >> 6;                      // wave = shift-row i, 0..8
  const int l    = t & 63;
  const int r    = l >> 5;                      // 0..1
  const int cidx = l & 31;
  const int w0   = cidx << 2;
  const int h    = h0 + r;

  __shared__ float4 sbuf[2][SCH * 404];         // 51,712 B

  const int c0 = half << 7;
  const float* f1b = f1 + ((size_t)b * CC + c0) * 8192;
  const float* f2b = f2 + ((size_t)b * CC + c0) * 8192;
  const float* Ab  = At + ((size_t)b * CC + c0) * 81 + i * 9;

  const float4 z4 = make_float4(0.f, 0.f, 0.f, 0.f);

  // stage 4-channel group g into buffer buf
  auto stage = [&](int g, int buf) {
    const int cg = g * SCH;
    for (int u = t; u < SCH * 404; u += 576) {
      const int cc  = u / 404;
      const int rem = u - cc * 404;
      float4 v = z4;
      if (rem < 340) {                          // f2: 10 rows x 34 chunks
        const int rr = rem / 34, kk = rem - rr * 34;
        const int gr = h0 + rr - 4;
        if ((unsigned)gr < 64u && kk >= 1 && kk <= 32)
          v = *(const float4*)(f2b + (size_t)(cg + cc) * 8192 + (gr << 7) +
                               ((kk - 1) << 2));
      } else {                                  // f1: 2 rows x 32 chunks
        const int idx = rem - 340;
        const int fr = idx >> 5, k2 = idx & 31;
        v = *(const float4*)(f1b + (size_t)(cg + cc) * 8192 +
                             ((h0 + fr) << 7) + (k2 << 2));
      }
      sbuf[buf][u] = v;
    }
  };

  float acc[9][4];
#pragma unroll
  for (int j = 0; j < 9; ++j)
#pragma unroll
    for (int k = 0; k < 4; ++k) acc[j][k] = 0.f;

  stage(0, 0);
  __syncthreads();

  for (int g = 0; g < 32; ++g) {
    if (g < 31) stage(g + 1, (g + 1) & 1);      // overlaps compute below

    const float4* cb = &sbuf[g & 1][0];
#pragma unroll
    for (int cc = 0; cc < SCH; ++cc) {
      const float4* chb = cb + cc * 404;
      const float4 f1v = chb[340 + (r << 5) + cidx];
      const float4 q0  = chb[(r + i) * 34 + cidx];
      const float4 q1  = chb[(r + i) * 34 + cidx + 1];
      const float4 q2  = chb[(r + i) * 34 + cidx + 2];

      alignas(16) float f2r[12];
      *(float4*)&f2r[0] = q0;
      *(float4*)&f2r[4] = q1;
      *(float4*)&f2r[8] = q2;
      alignas(16) const float xx[4] = {f1v.x, f1v.y, f1v.z, f1v.w};

      const float* av = Ab + (size_t)(g * SCH + cc) * 81;  // uniform s_load
#pragma unroll
      for (int j = 0; j < 9; ++j) {
        const float wj = av[j];
#pragma unroll
        for (int k = 0; k < 4; ++k) acc[j][k] += wj * (xx[k] * f2r[k + j]);
      }
    }
    __syncthreads();                            // buf[g&1] free; buf[^1] ready
  }

  float* dst = half ? part : out;
  const float inv = 1.0f / 256.0f;
#pragma unroll
  for (int j = 0; j < 9; ++j) {
    float4 o;
    o.x = acc[j][0] * inv;
    o.y = acc[j][1] * inv;
    o.z = acc[j][2] * inv;
    o.w = acc[j][3] * inv;
    *(float4*)(dst + (((size_t)(b * 81 + i * 9 + j) * 64 + h) << 7) + w0) = o;
  }
}

// ---------------------------------------------------------------------------
// Combine: out += channel-half-1 partial. 663,552 float4s, grid 2592 x 256.
// ---------------------------------------------------------------------------
__global__ __launch_bounds__(256) void combine_kernel(
    float* __restrict__ out, const float* __restrict__ part) {
  const size_t idx = (size_t)blockIdx.x * 256 + threadIdx.x;  // float4 index
  float4* o4       = (float4*)out;
  const float4* p4 = (const float4*)part;
  const float4 a = o4[idx], p = p4[idx];
  float4 rv;
  rv.x = a.x + p.x; rv.y = a.y + p.y; rv.z = a.z + p.z; rv.w = a.w + p.w;
  o4[idx] = rv;
}

// ---------------------------------------------------------------------------
extern "C" void kernel_launch(void* const* d_in, const int* in_sizes, int n_in,
                              void* d_out, int out_size, void* d_ws, size_t ws_size,
                              hipStream_t stream) {
  const float* feat1 = (const float*)d_in[0];
  const float* feat2 = (const float*)d_in[1];
  const float* w1    = (const float*)d_in[2];
  const float* b1    = (const float*)d_in[3];
  const float* w2    = (const float*)d_in[4];
  const float* b2    = (const float*)d_in[5];
  float* out = (float*)d_out;

  float* pooled = (float*)d_ws;                 // 82,944 floats
  float* At     = pooled + 82944;               // 82,944 floats
  float* cpart  = At + 82944;                   // 2,654,208 floats

  corr_pool_kernel<<<1024, 576, 0, stream>>>(feat1, feat2, pooled);
  mlp_kernel<<<4 * 81, 256, 0, stream>>>(pooled, w1, b1, w2, b2, At);
  out_kernel<<<256, 576, 0, stream>>>(feat1, feat2, At, out, cpart);
  combine_kernel<<<2592, 256, 0, stream>>>(out, cpart);
}